// Round 13
// baseline (124.439 us; speedup 1.0000x reference)
//
#include <hip/hip_runtime.h>

#define N_NODES 50000
#define N_EDGES 800000
#define D_FEAT 64

#define NPART 200                 // edge partitions
#define EPP (N_EDGES / NPART)     // 4000 edges per partition (exact)
#define BIG_SHIFT 9
#define BIG_NODES 512
#define NBIG ((N_NODES + BIG_NODES - 1) / BIG_NODES)  // 98 coarse bins
#define SCAP 12288                // LDS sort capacity (bin mean 8163, sigma ~90)

// ---- K1: per-partition LDS histogram over 98 coarse bins. No global atomics.
__global__ __launch_bounds__(1024) void part_hist_kernel(const int* __restrict__ dst,
                                                         int* __restrict__ histBB) {
    __shared__ int h[NBIG];
    int t = threadIdx.x, blk = blockIdx.x;
    if (t < NBIG) h[t] = 0;
    __syncthreads();
    int base = blk * EPP;
    for (int i = t; i < EPP; i += 1024)
        atomicAdd(&h[dst[base + i] >> BIG_SHIFT], 1);
    __syncthreads();
    if (t < NBIG) histBB[blk * NBIG + t] = h[t];
}

// ---- K2: per-bin exclusive scan over the 200 partitions (one block per bin).
__global__ void col_scan_kernel(const int* __restrict__ histBB,
                                int* __restrict__ baseBB,
                                int* __restrict__ binTot) {
    __shared__ int lds[256];
    int bin = blockIdx.x, t = threadIdx.x;
    int v = (t < NPART) ? histBB[t * NBIG + bin] : 0;
    lds[t] = v;
    __syncthreads();
    for (int off = 1; off < 256; off <<= 1) {
        int x = (t >= off) ? lds[t - off] : 0;
        __syncthreads();
        lds[t] += x;
        __syncthreads();
    }
    if (t < NPART) baseBB[t * NBIG + bin] = lds[t] - v;
    if (t == 255) binTot[bin] = lds[255];
}

// ---- K3: exclusive scan of 98 bin totals.
__global__ void bin_scan_kernel(const int* __restrict__ binTot, int* __restrict__ binBase) {
    __shared__ int wsum[2];
    int t = threadIdx.x;                  // 128 threads, 2 waves
    int v = (t < NBIG) ? binTot[t] : 0;
    int lane = t & 63, wave = t >> 6;
    int incl = v;
    #pragma unroll
    for (int o = 1; o < 64; o <<= 1) { int x = __shfl_up(incl, o); if (lane >= o) incl += x; }
    if (lane == 63) wsum[wave] = incl;
    __syncthreads();
    int base = (wave == 1) ? wsum[0] : 0;
    if (t < NBIG) binBase[t] = base + incl - v;
    if (t == NBIG - 1) binBase[NBIG] = base + incl;
}

// ---- K4: scatter packed (src | dstlow<<16) into coarse-bin staging segments.
// LDS cursors seeded with exact global bases -> zero global atomics; runs of
// ~41 contiguous words per (part,bin) -> full-line writebacks.
__global__ __launch_bounds__(1024) void part_scatter_kernel(const int* __restrict__ src,
                                                            const int* __restrict__ dst,
                                                            const int* __restrict__ baseBB,
                                                            const int* __restrict__ binBase,
                                                            unsigned int* __restrict__ staging) {
    __shared__ int cur[NBIG];
    int t = threadIdx.x, blk = blockIdx.x;
    if (t < NBIG) cur[t] = binBase[t] + baseBB[blk * NBIG + t];
    __syncthreads();
    int base = blk * EPP;
    for (int i = t; i < EPP; i += 1024) {
        int d = dst[base + i];
        int bin = d >> BIG_SHIFT;
        int pos = atomicAdd(&cur[bin], 1);           // LDS atomic
        staging[pos] = (unsigned int)src[base + i] |
                       ((unsigned int)(d & (BIG_NODES - 1)) << 16);
    }
}

// ---- K5: per-coarse-bin 512-wide counting sort -> u16 CSR (esorted) + offs.
__global__ __launch_bounds__(512) void sort512_kernel(const unsigned int* __restrict__ staging,
                                                      const int* __restrict__ binBase,
                                                      unsigned short* __restrict__ esorted,
                                                      int* __restrict__ offs) {
    __shared__ int cnt[BIG_NODES];
    __shared__ int cur[BIG_NODES];
    __shared__ unsigned short list[SCAP];
    __shared__ int wsum[8];
    int bin = blockIdx.x, t = threadIdx.x;
    int lo = binBase[bin], hi = binBase[bin + 1];
    int n = hi - lo;
    int nodeLo = bin << BIG_SHIFT;

    cnt[t] = 0;
    __syncthreads();
    for (int i = lo + t; i < hi; i += 512)
        atomicAdd(&cnt[(staging[i] >> 16) & (BIG_NODES - 1)], 1);
    __syncthreads();

    // exclusive scan of 512 counts: 8 waves shfl + wave-base combine
    int v = cnt[t];
    int lane = t & 63, wave = t >> 6;
    int incl = v;
    #pragma unroll
    for (int o = 1; o < 64; o <<= 1) { int x = __shfl_up(incl, o); if (lane >= o) incl += x; }
    if (lane == 63) wsum[wave] = incl;
    __syncthreads();
    int wbase = 0;
    #pragma unroll
    for (int w = 0; w < 8; ++w) wbase += (w < wave) ? wsum[w] : 0;
    int excl = wbase + incl - v;
    cur[t] = excl;

    int node = nodeLo + t;
    if (node < N_NODES) offs[node] = lo + excl;
    if (bin == NBIG - 1 && t == 0) offs[N_NODES] = N_EDGES;
    __syncthreads();

    if (n <= SCAP) {
        for (int i = lo + t; i < hi; i += 512) {
            unsigned int pk = staging[i];
            int p = atomicAdd(&cur[(pk >> 16) & (BIG_NODES - 1)], 1);
            list[p] = (unsigned short)pk;
        }
        __syncthreads();
        for (int i = t; i < n; i += 512)
            esorted[lo + i] = list[i];
    } else {
        // statistically unreachable; correct but slower
        for (int i = lo + t; i < hi; i += 512) {
            unsigned int pk = staging[i];
            int p = atomicAdd(&cur[(pk >> 16) & (BIG_NODES - 1)], 1);
            esorted[lo + p] = (unsigned short)pk;
        }
    }
}

// ---- K6: high-occupancy CSR pull. 16 lanes per node, float4 per lane,
// cooperative u16 id load + shfl broadcast, nontemporal out stores.
__global__ __launch_bounds__(256) void csr_pull_kernel(const float* __restrict__ xs,
                                                       const unsigned short* __restrict__ esorted,
                                                       const int* __restrict__ offs,
                                                       float* __restrict__ out) {
    int tid = blockIdx.x * 256 + threadIdx.x;   // grid exactly 50000*16
    int node = tid >> 4;
    int c = tid & 15;
    int beg = offs[node];
    int end = offs[node + 1];
    int deg = end - beg;
    float4 acc = make_float4(0.f, 0.f, 0.f, 0.f);
    for (int j0 = 0; j0 < deg; j0 += 16) {
        int rem = deg - j0;
        int m = rem < 16 ? rem : 16;
        int myid = (c < m) ? (int)__builtin_nontemporal_load(esorted + beg + j0 + c) : 0;
        if (m == 16) {
            #pragma unroll
            for (int k = 0; k < 16; ++k) {
                int s = __shfl(myid, k, 16);
                const float4 v = *reinterpret_cast<const float4*>(xs + s * D_FEAT + c * 4);
                acc.x += v.x; acc.y += v.y; acc.z += v.z; acc.w += v.w;
            }
        } else {
            for (int k = 0; k < m; ++k) {
                int s = __shfl(myid, k, 16);
                const float4 v = *reinterpret_cast<const float4*>(xs + s * D_FEAT + c * 4);
                acc.x += v.x; acc.y += v.y; acc.z += v.z; acc.w += v.w;
            }
        }
    }
    float inv = 1.0f / fmaxf((float)deg, 1.0f);
    float* op = out + (size_t)node * D_FEAT + c * 4;
    __builtin_nontemporal_store(acc.x * inv, op + 0);
    __builtin_nontemporal_store(acc.y * inv, op + 1);
    __builtin_nontemporal_store(acc.z * inv, op + 2);
    __builtin_nontemporal_store(acc.w * inv, op + 3);
}

// ---------------- Fallback (small ws): baseline atomic push ----------------

__global__ void scatter_kernel(const float* __restrict__ xs,
                               const int* __restrict__ src,
                               const int* __restrict__ dst,
                               float* __restrict__ sums,
                               float* __restrict__ counts) {
    int tid = blockIdx.x * blockDim.x + threadIdx.x;
    int e = tid >> 4;
    int c = tid & 15;
    if (e >= N_EDGES) return;
    int s = src[e];
    int d = dst[e];
    const float4 v = *reinterpret_cast<const float4*>(xs + (size_t)s * D_FEAT + c * 4);
    float* outp = sums + (size_t)d * D_FEAT + c * 4;
    atomicAdd(outp + 0, v.x);
    atomicAdd(outp + 1, v.y);
    atomicAdd(outp + 2, v.z);
    atomicAdd(outp + 3, v.w);
    if (c == 0) atomicAdd(counts + d, 1.0f);
}

__global__ void divide_kernel(float* __restrict__ out, const float* __restrict__ counts) {
    int tid = blockIdx.x * blockDim.x + threadIdx.x;
    if (tid >= N_NODES * D_FEAT / 4) return;
    int node = tid >> 4;
    float inv = 1.0f / fmaxf(counts[node], 1.0f);
    float4 v = reinterpret_cast<const float4*>(out)[tid];
    v.x *= inv; v.y *= inv; v.z *= inv; v.w *= inv;
    reinterpret_cast<float4*>(out)[tid] = v;
}

// ---------------- launch ----------------

extern "C" void kernel_launch(void* const* d_in, const int* in_sizes, int n_in,
                              void* d_out, int out_size, void* d_ws, size_t ws_size,
                              hipStream_t stream) {
    const float* xs  = (const float*)d_in[0];
    const int*   src = (const int*)d_in[1];
    const int*   dst = (const int*)d_in[2];
    float* out = (float*)d_out;

    size_t need = (size_t)(2 * NPART * NBIG + NBIG + (NBIG + 1) + (N_NODES + 1)) * sizeof(int)
                + (size_t)N_EDGES * sizeof(unsigned int)
                + (size_t)N_EDGES * sizeof(unsigned short);
    if (ws_size < need) {
        float* counts = (float*)d_ws;
        hipMemsetAsync(out, 0, (size_t)N_NODES * D_FEAT * sizeof(float), stream);
        hipMemsetAsync(counts, 0, (size_t)N_NODES * sizeof(float), stream);
        scatter_kernel<<<(N_EDGES * 16 + 255) / 256, 256, 0, stream>>>(xs, src, dst, out, counts);
        divide_kernel<<<(N_NODES * D_FEAT / 4 + 255) / 256, 256, 0, stream>>>(out, counts);
        return;
    }

    int* ws = (int*)d_ws;
    int* histBB  = ws;                           // NPART*NBIG
    int* baseBB  = histBB + NPART * NBIG;        // NPART*NBIG
    int* binTot  = baseBB + NPART * NBIG;        // NBIG
    int* binBase = binTot + NBIG;                // NBIG+1
    int* offs    = binBase + NBIG + 1;           // N_NODES+1
    unsigned int* staging = (unsigned int*)(offs + N_NODES + 1);      // N_EDGES u32
    unsigned short* esorted = (unsigned short*)(staging + N_EDGES);   // N_EDGES u16

    part_hist_kernel<<<NPART, 1024, 0, stream>>>(dst, histBB);
    col_scan_kernel<<<NBIG, 256, 0, stream>>>(histBB, baseBB, binTot);
    bin_scan_kernel<<<1, 128, 0, stream>>>(binTot, binBase);
    part_scatter_kernel<<<NPART, 1024, 0, stream>>>(src, dst, baseBB, binBase, staging);
    sort512_kernel<<<NBIG, 512, 0, stream>>>(staging, binBase, esorted, offs);
    csr_pull_kernel<<<(N_NODES * 16) / 256, 256, 0, stream>>>(xs, esorted, offs, out);
}